// Round 1
// baseline (428.649 us; speedup 1.0000x reference)
//
#include <hip/hip_runtime.h>

#define NB 32
#define NQ 2048
#define NK 2048
#define ND 128
#define QBLK 64
#define KBLK 32
#define MASKV -1000000.0f

typedef __attribute__((ext_vector_type(8))) short bf16x8;
typedef __attribute__((ext_vector_type(4))) short s16x4;
typedef __attribute__((ext_vector_type(4))) float f32x4;

__device__ __forceinline__ short f2bf(float f) {
  union { float f; unsigned u; } a; a.f = f;
  unsigned r = a.u + 0x7FFFu + ((a.u >> 16) & 1u);   // RNE
  return (short)(r >> 16);
}

// mask_idx dtype is ambiguous (numpy bool -> 1 byte, or int32). Detect on
// device: int32 0/1 arrays have zero bytes at offsets %4 != 0; uint8 random
// 0/1 arrays do not. flag=1 -> uint8, flag=0 -> int32.
__global__ void detect_mask_kernel(const unsigned char* __restrict__ m, int* flag) {
  __shared__ int s;
  if (threadIdx.x == 0) s = 0;
  __syncthreads();
  int acc = 0;
  for (int i = threadIdx.x; i < 65536; i += 256)
    if (i & 3) acc += m[i];
  atomicAdd(&s, acc);
  __syncthreads();
  if (threadIdx.x == 0) flag[0] = (s > 0) ? 1 : 0;
}

__global__ __launch_bounds__(256, 2)
void attn_fwd(const float* __restrict__ qp, const float* __restrict__ kp,
              const float* __restrict__ vp, const unsigned char* __restrict__ m8,
              float* __restrict__ op, const int* __restrict__ flag) {
  const int tid  = threadIdx.x;
  const int wv   = tid >> 6;
  const int lane = tid & 63;
  const int hi   = lane >> 4;
  const int lr   = lane & 15;
  const int b    = blockIdx.y;
  const int qw   = blockIdx.x * QBLK + wv * 16;   // this wave's 16 q-rows
  const bool is8 = (flag[0] != 0);
  const int* m32 = (const int*)m8;

  __shared__ __align__(16) short Kl[KBLK][136];   // +8 pad: 16B-aligned rows, ~2-way banks
  __shared__ __align__(16) short Vt[ND][40];      // V transposed, k-block xor swizzle
  __shared__ __align__(16) short Pl[4][16][40];   // per-wave P roundtrip

  // ---- Q fragments (A-frag: row=lr, d = dc*32 + hi*8 + j) ----
  bf16x8 qf[4];
  {
    const float* qrow = qp + ((size_t)b * NQ + (qw + lr)) * ND;
#pragma unroll
    for (int dc = 0; dc < 4; ++dc) {
      const float* s0 = qrow + dc * 32 + hi * 8;
      float4 x = *(const float4*)(s0);
      float4 y = *(const float4*)(s0 + 4);
      union { bf16x8 v; short h[8]; } u;
      u.h[0]=f2bf(x.x); u.h[1]=f2bf(x.y); u.h[2]=f2bf(x.z); u.h[3]=f2bf(x.w);
      u.h[4]=f2bf(y.x); u.h[5]=f2bf(y.y); u.h[6]=f2bf(y.z); u.h[7]=f2bf(y.w);
      qf[dc] = u.v;
    }
  }

  float mrun[4], lrun[4];
#pragma unroll
  for (int r = 0; r < 4; ++r) { mrun[r] = -1e30f; lrun[r] = 0.f; }
  f32x4 oacc[8];
#pragma unroll
  for (int dc = 0; dc < 8; ++dc) oacc[dc] = (f32x4){0.f, 0.f, 0.f, 0.f};

  const float scale = 0.08838834764831845f;  // 1/sqrt(128)
  const int c0 = tid & 31;   // V staging: d-group (4 cols)
  const int r0 = tid >> 5;   // V staging: k-group (4 rows)

  for (int kt = 0; kt < NK / KBLK; ++kt) {
    const size_t kvbase = ((size_t)b * NK + (size_t)kt * KBLK) * ND;
    __syncthreads();

    // ---- stage K tile [32][128] f32 -> bf16 LDS (coalesced float4 reads) ----
#pragma unroll
    for (int i = 0; i < 4; ++i) {
      int flat = (tid + i * 256) * 4;
      int row  = flat >> 7;
      int col  = flat & 127;
      float4 x = *(const float4*)(kp + kvbase + flat);
      s16x4 pk = (s16x4){f2bf(x.x), f2bf(x.y), f2bf(x.z), f2bf(x.w)};
      *(s16x4*)&Kl[row][col] = pk;
    }
    // ---- stage V transposed via in-register 4x4 transpose ----
    {
      float vv[4][4];
#pragma unroll
      for (int i = 0; i < 4; ++i) {
        float4 x = *(const float4*)(vp + kvbase + (4 * r0 + i) * ND + 4 * c0);
        vv[i][0]=x.x; vv[i][1]=x.y; vv[i][2]=x.z; vv[i][3]=x.w;
      }
#pragma unroll
      for (int j = 0; j < 4; ++j) {
        int d = 4 * c0 + j;
        int swzblk = (r0 >> 1) ^ (c0 & 3);          // k-block xor swizzle
        s16x4 pk = (s16x4){f2bf(vv[0][j]), f2bf(vv[1][j]), f2bf(vv[2][j]), f2bf(vv[3][j])};
        *(s16x4*)&Vt[d][4 * (r0 & 1) + 8 * swzblk] = pk;
      }
    }
    __syncthreads();

    // ---- S = Q·K^T : two 16-col groups x 4 d-chunks ----
    f32x4 s0 = (f32x4){0,0,0,0}, s1 = (f32x4){0,0,0,0};
#pragma unroll
    for (int dc = 0; dc < 4; ++dc) {
      bf16x8 k0 = *(const bf16x8*)&Kl[lr]     [dc * 32 + hi * 8];
      bf16x8 k1 = *(const bf16x8*)&Kl[16 + lr][dc * 32 + hi * 8];
      s0 = __builtin_amdgcn_mfma_f32_16x16x32_bf16(qf[dc], k0, s0, 0, 0, 0);
      s1 = __builtin_amdgcn_mfma_f32_16x16x32_bf16(qf[dc], k1, s1, 0, 0, 0);
    }

    // ---- scale + mask (S-layout: row = 4*hi + r, col = lr) ----
    float sv0[4], sv1[4];
    {
      const size_t mbase = ((size_t)b * NQ + (qw + 4 * hi)) * NK + (size_t)kt * KBLK + lr;
#pragma unroll
      for (int r = 0; r < 4; ++r) {
        size_t mi = mbase + (size_t)r * NK;
        unsigned a0, a1;
        if (is8) { a0 = m8[mi];            a1 = m8[mi + 16]; }
        else     { a0 = (unsigned)m32[mi]; a1 = (unsigned)m32[mi + 16]; }
        sv0[r] = a0 ? MASKV : s0[r] * scale;
        sv1[r] = a1 ? MASKV : s1[r] * scale;
      }
    }

    // ---- online softmax (row reductions across 16-lane groups) ----
#pragma unroll
    for (int r = 0; r < 4; ++r) {
      float tm = fmaxf(sv0[r], sv1[r]);
      tm = fmaxf(tm, __shfl_xor(tm, 1));
      tm = fmaxf(tm, __shfl_xor(tm, 2));
      tm = fmaxf(tm, __shfl_xor(tm, 4));
      tm = fmaxf(tm, __shfl_xor(tm, 8));
      float mnew = fmaxf(mrun[r], tm);
      float corr = __expf(mrun[r] - mnew);
      mrun[r] = mnew;
      float p0 = __expf(sv0[r] - mnew);
      float p1 = __expf(sv1[r] - mnew);
      float ps = p0 + p1;
      ps += __shfl_xor(ps, 1);
      ps += __shfl_xor(ps, 2);
      ps += __shfl_xor(ps, 4);
      ps += __shfl_xor(ps, 8);
      lrun[r] = lrun[r] * corr + ps;
#pragma unroll
      for (int dc = 0; dc < 8; ++dc) oacc[dc][r] *= corr;
      Pl[wv][4 * hi + r][lr]      = f2bf(p0);
      Pl[wv][4 * hi + r][16 + lr] = f2bf(p1);
    }

    // ---- O += P·V (A-frag of P: row=lr, k=hi*8+j; same-wave LDS RAW) ----
    bf16x8 pf = *(const bf16x8*)&Pl[wv][lr][hi * 8];
#pragma unroll
    for (int dc = 0; dc < 8; ++dc) {
      int dcol = dc * 16 + lr;
      bf16x8 vf = *(const bf16x8*)&Vt[dcol][8 * (hi ^ ((lr >> 2) & 3))];
      oacc[dc] = __builtin_amdgcn_mfma_f32_16x16x32_bf16(pf, vf, oacc[dc], 0, 0, 0);
    }
  }

  // ---- epilogue: O / l ----
#pragma unroll
  for (int r = 0; r < 4; ++r) {
    float inv = 1.0f / lrun[r];
    float* orow = op + ((size_t)b * NQ + (qw + 4 * hi + r)) * ND;
#pragma unroll
    for (int dc = 0; dc < 8; ++dc)
      orow[dc * 16 + lr] = oacc[dc][r] * inv;
  }
}

extern "C" void kernel_launch(void* const* d_in, const int* in_sizes, int n_in,
                              void* d_out, int out_size, void* d_ws, size_t ws_size,
                              hipStream_t stream) {
  const float* qp = (const float*)d_in[0];
  const float* kp = (const float*)d_in[1];
  const float* vp = (const float*)d_in[2];
  const unsigned char* mp = (const unsigned char*)d_in[3];
  float* op = (float*)d_out;
  int* flag = (int*)d_ws;

  detect_mask_kernel<<<1, 256, 0, stream>>>(mp, flag);
  dim3 grid(NQ / QBLK, NB);
  attn_fwd<<<grid, 256, 0, stream>>>(qp, kp, vp, mp, op, flag);
}

// Round 2
// 300.139 us; speedup vs baseline: 1.4282x; 1.4282x over previous
//
#include <hip/hip_runtime.h>

#define MASKV -1000000.0f

typedef __attribute__((ext_vector_type(8))) short bf16x8;
typedef __attribute__((ext_vector_type(4))) short s16x4;
typedef __attribute__((ext_vector_type(16))) float f32x16;

__device__ __forceinline__ unsigned cvt_pk_bf16(float lo, float hi_) {
  unsigned r;
  asm("v_cvt_pk_bf16_f32 %0, %1, %2" : "=v"(r) : "v"(lo), "v"(hi_));
  return r;
}

// mask_idx dtype ambiguity (uint8 bool vs int32): int32 0/1 arrays have zero
// bytes at offsets %4 != 0. flag=1 -> uint8, flag=0 -> int32.
__global__ void detect_mask_kernel(const unsigned char* __restrict__ m, int* flag) {
  __shared__ int s;
  if (threadIdx.x == 0) s = 0;
  __syncthreads();
  int acc = 0;
  for (int i = threadIdx.x; i < 65536; i += 256)
    if (i & 3) acc += m[i];
  atomicAdd(&s, acc);
  __syncthreads();
  if (threadIdx.x == 0) flag[0] = (s > 0) ? 1 : 0;
}

__global__ __launch_bounds__(512, 2)
void attn_fwd(const float* __restrict__ Qp, const float* __restrict__ Kp,
              const float* __restrict__ Vp, const unsigned char* __restrict__ M8,
              float* __restrict__ Op, const int* __restrict__ flag)
{
  const int tid  = threadIdx.x;
  const int lane = tid & 63;
  const int wv   = tid >> 6;        // 0..7
  const int hi   = lane >> 5;       // 0/1
  const int l31  = lane & 31;
  const int n    = blockIdx.x;
  // XCD-aware decode: batch b lands on XCD b&7 (round-robin dispatch),
  // so the 8 q-blocks of a batch share K/V tiles in one XCD's L2.
  const int b    = (n & 7) + 8 * (n >> 6);
  const int qt   = (n >> 3) & 7;
  const int q    = qt * 256 + wv * 32 + l31;   // this lane's q-row
  const bool is8 = (flag[0] != 0);

  __shared__ __align__(16) short Kl[64 * 128];   // K tile, XOR-swizzled
  __shared__ __align__(16) short Vt[128 * 64];   // V transposed, XOR-swizzled

  // ---- Q B-frags (col=q=lane&31, k-dim=d=dc*16+hi*8+j), pre-scaled ----
  const float scale = 0.08838834764831845f;   // 1/sqrt(128)
  bf16x8 qf[8];
  {
    const float* qrow = Qp + ((size_t)b * 2048 + q) * 128;
#pragma unroll
    for (int dc = 0; dc < 8; ++dc) {
      const int d0 = dc * 16 + hi * 8;
      float4 x = *(const float4*)(qrow + d0);
      float4 y = *(const float4*)(qrow + d0 + 4);
      union { bf16x8 v; unsigned u[4]; } uu;
      uu.u[0] = cvt_pk_bf16(x.x * scale, x.y * scale);
      uu.u[1] = cvt_pk_bf16(x.z * scale, x.w * scale);
      uu.u[2] = cvt_pk_bf16(y.x * scale, y.y * scale);
      uu.u[3] = cvt_pk_bf16(y.z * scale, y.w * scale);
      qf[dc] = uu.v;
    }
  }

  f32x16 oacc[4];
#pragma unroll
  for (int g = 0; g < 4; ++g)
#pragma unroll
    for (int r = 0; r < 16; ++r) oacc[g][r] = 0.f;

  float mrun = -1e30f, lrun = 0.f;
  const unsigned char* mrow8  = M8 + ((size_t)b * 2048 + q) * (size_t)2048;
  const int*           mrow32 = (const int*)M8 + ((size_t)b * 2048 + q) * (size_t)2048;

  const int xk = 8 * (l31 & 15);   // K-lds XOR key (shorts)
  const int xv = 8 * (l31 >> 2);   // V-lds XOR key (shorts)

  for (int kt = 0; kt < 32; ++kt) {
    const size_t kvbase = ((size_t)b * 2048 + (size_t)kt * 64) * 128;
    __syncthreads();

    // ---- stage K [64][128] f32->bf16, swizzled ----
#pragma unroll
    for (int i = 0; i < 4; ++i) {
      int flat = tid + i * 512;
      int row  = flat >> 5;
      int col  = (flat & 31) * 4;
      float4 x = *(const float4*)(Kp + kvbase + row * 128 + col);
      union { s16x4 v; unsigned u[2]; } pk;
      pk.u[0] = cvt_pk_bf16(x.x, x.y);
      pk.u[1] = cvt_pk_bf16(x.z, x.w);
      *(s16x4*)&Kl[row * 128 + (col ^ (8 * (row & 15)))] = pk.v;
    }
    // ---- stage V transposed (in-register 4x4), swizzled ----
    {
      const int db = tid & 31, kb = tid >> 5;   // 32 x 16 blocks of 4x4
      const int d0 = db * 4,  k0 = kb * 4;
      union { float4 v; float f[4]; } r0, r1, r2, r3;
      r0.v = *(const float4*)(Vp + kvbase + (k0 + 0) * 128 + d0);
      r1.v = *(const float4*)(Vp + kvbase + (k0 + 1) * 128 + d0);
      r2.v = *(const float4*)(Vp + kvbase + (k0 + 2) * 128 + d0);
      r3.v = *(const float4*)(Vp + kvbase + (k0 + 3) * 128 + d0);
      const int cs = k0 ^ (8 * (db & 7));
#pragma unroll
      for (int j = 0; j < 4; ++j) {
        union { s16x4 v; unsigned u[2]; } pk;
        pk.u[0] = cvt_pk_bf16(r0.f[j], r1.f[j]);
        pk.u[1] = cvt_pk_bf16(r2.f[j], r3.f[j]);
        *(s16x4*)&Vt[(d0 + j) * 64 + cs] = pk.v;
      }
    }
    __syncthreads();

    // ---- S^T = K · Q^T (swapped): lane holds S[k][q=l31], k via crow ----
    f32x16 s0m, s1m;
#pragma unroll
    for (int r = 0; r < 16; ++r) { s0m[r] = 0.f; s1m[r] = 0.f; }
#pragma unroll
    for (int dc = 0; dc < 8; ++dc) {
      const int colb = (dc * 16 + hi * 8) ^ xk;
      bf16x8 a0 = *(const bf16x8*)&Kl[l31 * 128 + colb];
      bf16x8 a1 = *(const bf16x8*)&Kl[(32 + l31) * 128 + colb];
      s0m = __builtin_amdgcn_mfma_f32_32x32x16_bf16(a0, qf[dc], s0m, 0, 0, 0);
      s1m = __builtin_amdgcn_mfma_f32_32x32x16_bf16(a1, qf[dc], s1m, 0, 0, 0);
    }

    // ---- mask: reg r <-> k = 32*kk + (r&3) + 8*(r>>2) + 4*hi ----
    float p0[16], p1[16];
    const int kb0 = kt * 64;
    if (is8) {
#pragma unroll
      for (int m = 0; m < 4; ++m) {
        unsigned w0 = *(const unsigned*)(mrow8 + kb0 + hi * 4 + m * 8);
        unsigned w1 = *(const unsigned*)(mrow8 + kb0 + 32 + hi * 4 + m * 8);
#pragma unroll
        for (int e = 0; e < 4; ++e) {
          p0[4 * m + e] = ((w0 >> (8 * e)) & 0xffu) ? MASKV : s0m[4 * m + e];
          p1[4 * m + e] = ((w1 >> (8 * e)) & 0xffu) ? MASKV : s1m[4 * m + e];
        }
      }
    } else {
#pragma unroll
      for (int m = 0; m < 4; ++m) {
        int4 w0 = *(const int4*)(mrow32 + kb0 + hi * 4 + m * 8);
        int4 w1 = *(const int4*)(mrow32 + kb0 + 32 + hi * 4 + m * 8);
        p0[4 * m + 0] = w0.x ? MASKV : s0m[4 * m + 0];
        p0[4 * m + 1] = w0.y ? MASKV : s0m[4 * m + 1];
        p0[4 * m + 2] = w0.z ? MASKV : s0m[4 * m + 2];
        p0[4 * m + 3] = w0.w ? MASKV : s0m[4 * m + 3];
        p1[4 * m + 0] = w1.x ? MASKV : s1m[4 * m + 0];
        p1[4 * m + 1] = w1.y ? MASKV : s1m[4 * m + 1];
        p1[4 * m + 2] = w1.z ? MASKV : s1m[4 * m + 2];
        p1[4 * m + 3] = w1.w ? MASKV : s1m[4 * m + 3];
      }
    }

    // ---- online softmax, lane-local row + one cross-half exchange ----
    float tm = p0[0];
#pragma unroll
    for (int r = 1; r < 16; ++r) tm = fmaxf(tm, p0[r]);
#pragma unroll
    for (int r = 0; r < 16; ++r) tm = fmaxf(tm, p1[r]);
    tm = fmaxf(tm, __shfl_xor(tm, 32));

    if (__any(tm > mrun + 8.0f)) {        // defer-max (T13)
      float mnew = fmaxf(mrun, tm);
      float corr = __expf(mrun - mnew);
      mrun = mnew;
      lrun *= corr;
#pragma unroll
      for (int g = 0; g < 4; ++g)
#pragma unroll
        for (int r = 0; r < 16; ++r) oacc[g][r] *= corr;
    }

    float psum = 0.f;
#pragma unroll
    for (int r = 0; r < 16; ++r) { p0[r] = __expf(p0[r] - mrun); psum += p0[r]; }
#pragma unroll
    for (int r = 0; r < 16; ++r) { p1[r] = __expf(p1[r] - mrun); psum += p1[r]; }
    psum += __shfl_xor(psum, 32);
    lrun += psum;

    // ---- P (S^T C-layout) -> P^T B-frags, in-register ----
    unsigned pk0[8], pk1[8];
#pragma unroll
    for (int i = 0; i < 8; ++i) {
      pk0[i] = cvt_pk_bf16(p0[2 * i], p0[2 * i + 1]);
      pk1[i] = cvt_pk_bf16(p1[2 * i], p1[2 * i + 1]);
    }
    bf16x8 pa[4];
#pragma unroll
    for (int ks = 0; ks < 4; ++ks) {
      const int base = 4 * (ks & 1);
      unsigned o0, o1, sd0, sd1;
      if (ks < 2) {
        o0  = hi ? pk0[base + 2] : pk0[base + 0];
        o1  = hi ? pk0[base + 3] : pk0[base + 1];
        sd0 = hi ? pk0[base + 0] : pk0[base + 2];
        sd1 = hi ? pk0[base + 1] : pk0[base + 3];
      } else {
        o0  = hi ? pk1[base + 2] : pk1[base + 0];
        o1  = hi ? pk1[base + 3] : pk1[base + 1];
        sd0 = hi ? pk1[base + 0] : pk1[base + 2];
        sd1 = hi ? pk1[base + 1] : pk1[base + 3];
      }
      unsigned rec0 = (unsigned)__shfl_xor((int)sd0, 32);
      unsigned rec1 = (unsigned)__shfl_xor((int)sd1, 32);
      union { bf16x8 v; unsigned u[4]; } uu;
      uu.u[0] = hi ? rec0 : o0;
      uu.u[1] = hi ? rec1 : o1;
      uu.u[2] = hi ? o0 : rec0;
      uu.u[3] = hi ? o1 : rec1;
      pa[ks] = uu.v;
    }

    // ---- O^T += V^T · P^T (corr stays lane-local: col=q) ----
#pragma unroll
    for (int g = 0; g < 4; ++g) {
      const int drow = g * 32 + l31;
#pragma unroll
      for (int ks = 0; ks < 4; ++ks) {
        bf16x8 va = *(const bf16x8*)&Vt[drow * 64 + ((ks * 16 + hi * 8) ^ xv)];
        oacc[g] = __builtin_amdgcn_mfma_f32_32x32x16_bf16(va, pa[ks], oacc[g], 0, 0, 0);
      }
    }
  }

  // ---- epilogue: O[q][d] = oacc/l; d = 32g + 4hi + 8m + e ----
  const float inv = 1.0f / lrun;
  float* orow = Op + ((size_t)b * 2048 + q) * 128;
#pragma unroll
  for (int g = 0; g < 4; ++g) {
#pragma unroll
    for (int m = 0; m < 4; ++m) {
      float4 o;
      o.x = oacc[g][4 * m + 0] * inv;
      o.y = oacc[g][4 * m + 1] * inv;
      o.z = oacc[g][4 * m + 2] * inv;
      o.w = oacc[g][4 * m + 3] * inv;
      *(float4*)(orow + g * 32 + hi * 4 + m * 8) = o;
    }
  }
}

extern "C" void kernel_launch(void* const* d_in, const int* in_sizes, int n_in,
                              void* d_out, int out_size, void* d_ws, size_t ws_size,
                              hipStream_t stream) {
  const float* qp = (const float*)d_in[0];
  const float* kp = (const float*)d_in[1];
  const float* vp = (const float*)d_in[2];
  const unsigned char* mp = (const unsigned char*)d_in[3];
  float* op = (float*)d_out;
  int* flag = (int*)d_ws;

  detect_mask_kernel<<<1, 256, 0, stream>>>(mp, flag);
  attn_fwd<<<256, 512, 0, stream>>>(qp, kp, vp, mp, op, flag);
}

// Round 3
// 292.926 us; speedup vs baseline: 1.4633x; 1.0246x over previous
//
#include <hip/hip_runtime.h>

typedef __attribute__((ext_vector_type(8))) short bf16x8;
typedef __attribute__((ext_vector_type(4))) short s16x4;
typedef __attribute__((ext_vector_type(16))) float f32x16;

#define LOG2E 1.4426950408889634f
#define MASKV2 (-1442695.0f)          // -1e6 * log2(e): exp2 domain

__device__ __forceinline__ unsigned cvt_pk_bf16(float lo, float hi_) {
  unsigned r;
  asm("v_cvt_pk_bf16_f32 %0, %1, %2" : "=v"(r) : "v"(lo), "v"(hi_));
  return r;
}

// mask_idx dtype ambiguity (uint8 bool vs int32): int32 0/1 arrays have zero
// bytes at offsets %4 != 0. flag=1 -> uint8, flag=0 -> int32.
__global__ void detect_mask_kernel(const unsigned char* __restrict__ m, int* flag) {
  __shared__ int s;
  if (threadIdx.x == 0) s = 0;
  __syncthreads();
  int acc = 0;
  for (int i = threadIdx.x; i < 65536; i += 256)
    if (i & 3) acc += m[i];
  atomicAdd(&s, acc);
  __syncthreads();
  if (threadIdx.x == 0) flag[0] = (s > 0) ? 1 : 0;
}

__global__ __launch_bounds__(512, 2)
void attn_fwd(const float* __restrict__ Qp, const float* __restrict__ Kp,
              const float* __restrict__ Vp, const unsigned char* __restrict__ M8,
              float* __restrict__ Op, const int* __restrict__ flag)
{
  const int tid  = threadIdx.x;
  const int lane = tid & 63;
  const int wv   = tid >> 6;        // 0..7
  const int hi   = lane >> 5;       // 0/1
  const int l31  = lane & 31;
  const int n    = blockIdx.x;
  // XCD-aware decode: all 8 q-blocks of batch b land on XCD b&7, sharing
  // that batch's K/V (2 MB) in one XCD's L2.
  const int b    = (n & 7) + 8 * (n >> 6);
  const int qt   = (n >> 3) & 7;
  const int q    = qt * 256 + wv * 32 + l31;   // this lane's q-row
  const bool is8 = (flag[0] != 0);

  __shared__ __align__(16) short Kl[2][64 * 128];   // K tiles, XOR-swizzled
  __shared__ __align__(16) short Vt[2][128 * 64];   // V^T tiles, XOR-swizzled

  // ---- Q B-frags (col=q=lane&31, k-dim=d=dc*16+hi*8+j), scale*log2e folded ----
  const float qscale = 0.08838834764831845f * LOG2E;
  bf16x8 qf[8];
  {
    const float* qrow = Qp + ((size_t)b * 2048 + q) * 128;
#pragma unroll
    for (int dc = 0; dc < 8; ++dc) {
      const int d0 = dc * 16 + hi * 8;
      float4 x = *(const float4*)(qrow + d0);
      float4 y = *(const float4*)(qrow + d0 + 4);
      union { bf16x8 v; unsigned u[4]; } uu;
      uu.u[0] = cvt_pk_bf16(x.x * qscale, x.y * qscale);
      uu.u[1] = cvt_pk_bf16(x.z * qscale, x.w * qscale);
      uu.u[2] = cvt_pk_bf16(y.x * qscale, y.y * qscale);
      uu.u[3] = cvt_pk_bf16(y.z * qscale, y.w * qscale);
      qf[dc] = uu.v;
    }
  }

  f32x16 oacc[4];
#pragma unroll
  for (int g = 0; g < 4; ++g)
#pragma unroll
    for (int r = 0; r < 16; ++r) oacc[g][r] = 0.f;

  float mrun = -1e30f, lrun = 0.f;
  const unsigned char* mrow8  = M8 + ((size_t)b * 2048 + q) * (size_t)2048;
  const int*           mrow32 = (const int*)M8 + ((size_t)b * 2048 + q) * (size_t)2048;

  const int xk = 8 * (l31 & 15);   // K-lds XOR key (shorts)
  const int xv = 8 * (l31 >> 2);   // V-lds XOR key (shorts)
  const int db = tid & 31, kb = tid >> 5;   // V staging: 32 x 16 blocks of 4x4
  const size_t kvrow0 = (size_t)b * 2048 * 128;

  // K staging address pieces (this thread covers 4 chunks)
  const int krow0 = tid >> 5;              // +16 per chunk
  const int kcol0 = (tid & 31) * 4;

  // ---- prologue: stage tile 0 into buf 0 ----
  {
#pragma unroll
    for (int i = 0; i < 4; ++i) {
      const int row = krow0 + i * 16;
      float4 x = *(const float4*)(Kp + kvrow0 + row * 128 + kcol0);
      union { s16x4 v; unsigned u[2]; } pk;
      pk.u[0] = cvt_pk_bf16(x.x, x.y);
      pk.u[1] = cvt_pk_bf16(x.z, x.w);
      *(s16x4*)&Kl[0][row * 128 + (kcol0 ^ (8 * (row & 15)))] = pk.v;
    }
    union { float4 v; float f[4]; } r0, r1, r2, r3;
    r0.v = *(const float4*)(Vp + kvrow0 + (kb * 4 + 0) * 128 + db * 4);
    r1.v = *(const float4*)(Vp + kvrow0 + (kb * 4 + 1) * 128 + db * 4);
    r2.v = *(const float4*)(Vp + kvrow0 + (kb * 4 + 2) * 128 + db * 4);
    r3.v = *(const float4*)(Vp + kvrow0 + (kb * 4 + 3) * 128 + db * 4);
    const int cs = (kb * 4) ^ (8 * (db & 7));
#pragma unroll
    for (int j = 0; j < 4; ++j) {
      union { s16x4 v; unsigned u[2]; } pk;
      pk.u[0] = cvt_pk_bf16(r0.f[j], r1.f[j]);
      pk.u[1] = cvt_pk_bf16(r2.f[j], r3.f[j]);
      *(s16x4*)&Vt[0][(db * 4 + j) * 64 + cs] = pk.v;
    }
  }
  __syncthreads();

  for (int kt = 0; kt < 32; ++kt) {
    const int cur = kt & 1;
    const short* klb = &Kl[cur][0];
    const short* vtb = &Vt[cur][0];

    // ---- prefetch this tile's mask dwords (consumed after QK) ----
    unsigned mw[8];
    if (is8) {
#pragma unroll
      for (int m = 0; m < 4; ++m) {
        mw[m]     = *(const unsigned*)(mrow8 + kt * 64 + hi * 4 + m * 8);
        mw[4 + m] = *(const unsigned*)(mrow8 + kt * 64 + 32 + hi * 4 + m * 8);
      }
    }

    // ---- prefetch next K/V tile into registers (consumed at iteration end) ----
    const int ktn = (kt < 31) ? kt + 1 : 31;
    const size_t nb = kvrow0 + (size_t)ktn * 64 * 128;
    float4 kreg[4];
#pragma unroll
    for (int i = 0; i < 4; ++i)
      kreg[i] = *(const float4*)(Kp + nb + (krow0 + i * 16) * 128 + kcol0);
    float4 vreg[4];
#pragma unroll
    for (int i = 0; i < 4; ++i)
      vreg[i] = *(const float4*)(Vp + nb + (kb * 4 + i) * 128 + db * 4);

    // ---- S^T = K · Q^T (swapped): lane holds S[k][q=l31] ----
    f32x16 s0m, s1m;
#pragma unroll
    for (int r = 0; r < 16; ++r) { s0m[r] = 0.f; s1m[r] = 0.f; }
    __builtin_amdgcn_s_setprio(1);
#pragma unroll
    for (int dc = 0; dc < 8; ++dc) {
      const int colb = (dc * 16 + hi * 8) ^ xk;
      bf16x8 a0 = *(const bf16x8*)&klb[l31 * 128 + colb];
      bf16x8 a1 = *(const bf16x8*)&klb[(32 + l31) * 128 + colb];
      s0m = __builtin_amdgcn_mfma_f32_32x32x16_bf16(a0, qf[dc], s0m, 0, 0, 0);
      s1m = __builtin_amdgcn_mfma_f32_32x32x16_bf16(a1, qf[dc], s1m, 0, 0, 0);
    }
    __builtin_amdgcn_s_setprio(0);

    // ---- mask: reg r <-> k = 32*kk + (r&3) + 8*(r>>2) + 4*hi ----
    float p0[16], p1[16];
    if (is8) {
#pragma unroll
      for (int m = 0; m < 4; ++m) {
#pragma unroll
        for (int e = 0; e < 4; ++e) {
          p0[4 * m + e] = ((mw[m]     >> (8 * e)) & 0xffu) ? MASKV2 : s0m[4 * m + e];
          p1[4 * m + e] = ((mw[4 + m] >> (8 * e)) & 0xffu) ? MASKV2 : s1m[4 * m + e];
        }
      }
    } else {
#pragma unroll
      for (int m = 0; m < 4; ++m) {
        int4 w0 = *(const int4*)(mrow32 + kt * 64 + hi * 4 + m * 8);
        int4 w1 = *(const int4*)(mrow32 + kt * 64 + 32 + hi * 4 + m * 8);
        p0[4 * m + 0] = w0.x ? MASKV2 : s0m[4 * m + 0];
        p0[4 * m + 1] = w0.y ? MASKV2 : s0m[4 * m + 1];
        p0[4 * m + 2] = w0.z ? MASKV2 : s0m[4 * m + 2];
        p0[4 * m + 3] = w0.w ? MASKV2 : s0m[4 * m + 3];
        p1[4 * m + 0] = w1.x ? MASKV2 : s1m[4 * m + 0];
        p1[4 * m + 1] = w1.y ? MASKV2 : s1m[4 * m + 1];
        p1[4 * m + 2] = w1.z ? MASKV2 : s1m[4 * m + 2];
        p1[4 * m + 3] = w1.w ? MASKV2 : s1m[4 * m + 3];
      }
    }

    // ---- online softmax in exp2 domain, lane-local + one cross-half swap ----
    float tm = p0[0];
#pragma unroll
    for (int r = 1; r < 16; ++r) tm = fmaxf(tm, p0[r]);
#pragma unroll
    for (int r = 0; r < 16; ++r) tm = fmaxf(tm, p1[r]);
    tm = fmaxf(tm, __shfl_xor(tm, 32));

    if (__any(tm > mrun + 8.0f)) {        // defer-max (T13)
      float mnew = fmaxf(mrun, tm);
      float corr = __builtin_amdgcn_exp2f(mrun - mnew);
      mrun = mnew;
      lrun *= corr;
#pragma unroll
      for (int g = 0; g < 4; ++g)
#pragma unroll
        for (int r = 0; r < 16; ++r) oacc[g][r] *= corr;
    }

    float psum = 0.f;
#pragma unroll
    for (int r = 0; r < 16; ++r) { p0[r] = __builtin_amdgcn_exp2f(p0[r] - mrun); psum += p0[r]; }
#pragma unroll
    for (int r = 0; r < 16; ++r) { p1[r] = __builtin_amdgcn_exp2f(p1[r] - mrun); psum += p1[r]; }
    psum += __shfl_xor(psum, 32);
    lrun += psum;

    // ---- P (S^T C-layout) -> P^T B-frags, in-register ----
    unsigned pk0[8], pk1[8];
#pragma unroll
    for (int i = 0; i < 8; ++i) {
      pk0[i] = cvt_pk_bf16(p0[2 * i], p0[2 * i + 1]);
      pk1[i] = cvt_pk_bf16(p1[2 * i], p1[2 * i + 1]);
    }
    bf16x8 pa[4];
#pragma unroll
    for (int ks = 0; ks < 4; ++ks) {
      const int base = 4 * (ks & 1);
      unsigned o0, o1, sd0, sd1;
      if (ks < 2) {
        o0  = hi ? pk0[base + 2] : pk0[base + 0];
        o1  = hi ? pk0[base + 3] : pk0[base + 1];
        sd0 = hi ? pk0[base + 0] : pk0[base + 2];
        sd1 = hi ? pk0[base + 1] : pk0[base + 3];
      } else {
        o0  = hi ? pk1[base + 2] : pk1[base + 0];
        o1  = hi ? pk1[base + 3] : pk1[base + 1];
        sd0 = hi ? pk1[base + 0] : pk1[base + 2];
        sd1 = hi ? pk1[base + 1] : pk1[base + 3];
      }
      unsigned rec0 = (unsigned)__shfl_xor((int)sd0, 32);
      unsigned rec1 = (unsigned)__shfl_xor((int)sd1, 32);
      union { bf16x8 v; unsigned u[4]; } uu;
      uu.u[0] = hi ? rec0 : o0;
      uu.u[1] = hi ? rec1 : o1;
      uu.u[2] = hi ? o0 : rec0;
      uu.u[3] = hi ? o1 : rec1;
      pa[ks] = uu.v;
    }

    // ---- O^T += V^T · P^T ----
    __builtin_amdgcn_s_setprio(1);
#pragma unroll
    for (int g = 0; g < 4; ++g) {
      const int drow = g * 32 + l31;
#pragma unroll
      for (int ks = 0; ks < 4; ++ks) {
        bf16x8 va = *(const bf16x8*)&vtb[drow * 64 + ((ks * 16 + hi * 8) ^ xv)];
        oacc[g] = __builtin_amdgcn_mfma_f32_32x32x16_bf16(va, pa[ks], oacc[g], 0, 0, 0);
      }
    }
    __builtin_amdgcn_s_setprio(0);

    // ---- write staged tile (regs -> buf[cur^1]) ----
    {
      short* kln = &Kl[cur ^ 1][0];
      short* vtn = &Vt[cur ^ 1][0];
#pragma unroll
      for (int i = 0; i < 4; ++i) {
        const int row = krow0 + i * 16;
        union { s16x4 v; unsigned u[2]; } pk;
        pk.u[0] = cvt_pk_bf16(kreg[i].x, kreg[i].y);
        pk.u[1] = cvt_pk_bf16(kreg[i].z, kreg[i].w);
        *(s16x4*)&kln[row * 128 + (kcol0 ^ (8 * (row & 15)))] = pk.v;
      }
      const int cs = (kb * 4) ^ (8 * (db & 7));
#pragma unroll
      for (int j = 0; j < 4; ++j) {
        union { s16x4 v; unsigned u[2]; } pk;
        union { float4 v; float f[4]; } a0, a1, a2, a3;
        a0.v = vreg[0]; a1.v = vreg[1]; a2.v = vreg[2]; a3.v = vreg[3];
        pk.u[0] = cvt_pk_bf16(a0.f[j], a1.f[j]);
        pk.u[1] = cvt_pk_bf16(a2.f[j], a3.f[j]);
        *(s16x4*)&vtn[(db * 4 + j) * 64 + cs] = pk.v;
      }
    }
    __syncthreads();
  }

  // ---- epilogue: O[q][d] = oacc/l; d = 32g + 4hi + 8m + e ----
  const float inv = 1.0f / lrun;
  float* orow = Op + ((size_t)b * 2048 + q) * 128;
#pragma unroll
  for (int g = 0; g < 4; ++g) {
#pragma unroll
    for (int m = 0; m < 4; ++m) {
      float4 o;
      o.x = oacc[g][4 * m + 0] * inv;
      o.y = oacc[g][4 * m + 1] * inv;
      o.z = oacc[g][4 * m + 2] * inv;
      o.w = oacc[g][4 * m + 3] * inv;
      *(float4*)(orow + g * 32 + hi * 4 + m * 8) = o;
    }
  }
}

extern "C" void kernel_launch(void* const* d_in, const int* in_sizes, int n_in,
                              void* d_out, int out_size, void* d_ws, size_t ws_size,
                              hipStream_t stream) {
  const float* qp = (const float*)d_in[0];
  const float* kp = (const float*)d_in[1];
  const float* vp = (const float*)d_in[2];
  const unsigned char* mp = (const unsigned char*)d_in[3];
  float* op = (float*)d_out;
  int* flag = (int*)d_ws;

  detect_mask_kernel<<<1, 256, 0, stream>>>(mp, flag);
  attn_fwd<<<256, 512, 0, stream>>>(qp, kp, vp, mp, op, flag);
}